// Round 1
// baseline (870.661 us; speedup 1.0000x reference)
//
#include <hip/hip_runtime.h>
#include <stdint.h>

// Problem constants: N=500000, D_IN=128, R=256, D_OUT=64, U=10000
#define N_ROWS 500000
#define U_DIM 10000
#define EPSV 1e-8f
#define NT16 31250            // 16-row wave-tiles (exact: 500000/16)

typedef __attribute__((ext_vector_type(8))) short bf16x8;   // 8 bf16 = 4 VGPRs
typedef __attribute__((ext_vector_type(4))) float f32x4;    // MFMA 16x16 accumulator

__device__ __forceinline__ short f2bf(float f) {
  unsigned u = __float_as_uint(f);
  u += 0x7fffu + ((u >> 16) & 1u);
  return (short)(u >> 16);
}
__device__ __forceinline__ float bf2f(short s) {
  return __uint_as_float(((unsigned)(unsigned short)s) << 16);
}

// Packed weight layouts in d_ws (shorts), frag-major (one wave load = 1 KB):
//   L0: [rc=8][mat=2][ct=2][kt=4][lane=64][u=8]  @ 0      (128 KB; 16 KB/rc chunk)
//   L1: [rc=8][ct1=4][mat=3][lane=64][u=8]       @ 65536  (96 KB)
// lane = q*16 + n;  element: c/o = ct*16+n,  k/j = kt*32 + q*8 + u.
__global__ void prep_weights(const float* __restrict__ Wmu0,
                             const float* __restrict__ Wlv0,
                             const float* __restrict__ Wmu1,
                             const float* __restrict__ Wlv1,
                             short* __restrict__ wgt) {
  int i = blockIdx.x * blockDim.x + threadIdx.x;
  if (i < 32768) {                       // L0 element: k = i>>8 (0..127), c = i&255
    int c = i & 255, k = i >> 8;
    int rc = c >> 5, ct = (c >> 4) & 1, n = c & 15;
    int kt = k >> 5, q = (k >> 3) & 3, u = k & 7;
    int lane = q * 16 + n;
    float mu = Wmu0[k * 256 + c];
    float ev = __expf(Wlv0[k * 256 + c]);
    wgt[((((rc * 2 + 0) * 2 + ct) * 4 + kt) * 64 + lane) * 8 + u] = f2bf(mu);
    wgt[((((rc * 2 + 1) * 2 + ct) * 4 + kt) * 64 + lane) * 8 + u] = f2bf(ev);
  } else if (i < 49152) {                // L1 element: j = (i-32768)>>6, o = &63
    int i2 = i - 32768;
    int o = i2 & 63, j = i2 >> 6;
    int rc = j >> 5, q = (j >> 3) & 3, u = j & 7;
    int ct1 = o >> 4, n = o & 15;
    int lane = q * 16 + n;
    float mu = Wmu1[j * 64 + o];
    float ev = __expf(Wlv1[j * 64 + o]);
    int b = 65536 + (((rc * 4 + ct1) * 3 + 0) * 64 + lane) * 8 + u;
    wgt[b]        = f2bf(mu);            // mat 0: mu1
    wgt[b + 512]  = f2bf(mu * mu + ev);  // mat 1: mu1^2 + var
    wgt[b + 1024] = f2bf(ev);            // mat 2: var
  }
}

// Fused 2-layer VB kernel, barrier-free main loop (R5 restructure).
// Block = 512 thr (8 waves), 1 block/CU (151.5 KB LDS). ALL L0 weights
// (128 KB) are staged into LDS ONCE per block via global_load_lds (16
// segments x 512 thr x 16 B = 8 KB each), followed by the ONLY
// __syncthreads in the kernel. Each wave then grid-strides over 16-row
// tiles with no further synchronization: L0 B-frags from LDS (multicast),
// L1 B-frags direct from global (12 KB/rc slice, L2/L1-cache resident).
// Next-tile X loads (8 x float4) are issued before the rc loop so their
// ~900-cyc HBM latency hides under ~3000 cyc of MFMA work (T14 pattern;
// the xr register WAR dependency orders them after the current converts).
__global__ __launch_bounds__(512, 2) void vb_fused(
    const float* __restrict__ X, const int* __restrict__ Xidx,
    const short* __restrict__ wgt, float* __restrict__ out) {
  __shared__ __align__(16) short stage[65536];      // full L0 set, 128 KB
  __shared__ __align__(16) short ldsM[8][16 * 40];  // per-wave transpose, stride 40
  __shared__ __align__(16) short ldsV[8][16 * 40];

  const int tid  = threadIdx.x;
  const int w    = tid >> 6;
  const int lane = tid & 63;
  const int n    = lane & 15;
  const int q    = lane >> 4;
  const int lane8 = lane * 8;

  // ---- one-time stage of all L0 weights (LDS dest is wave-uniform base;
  // HW adds lane*16 — matches global src base + tid*16, per m104/m108)
  {
    const char* gbase = (const char*)wgt;
#pragma unroll
    for (int s = 0; s < 16; ++s) {
      __builtin_amdgcn_global_load_lds(
          (const __attribute__((address_space(1))) unsigned int*)
              (gbase + s * 8192 + tid * 16),
          (__attribute__((address_space(3))) unsigned int*)
              ((char*)&stage[0] + s * 8192 + (w << 10)),
          16, 0, 0);
    }
  }
  __syncthreads();   // compiler drains vmcnt(0) first -> stage complete

  const int gw = blockIdx.x * 8 + w;     // 2048 wave slots, stride the tiles
  int T = gw;                            // always < NT16 (2048 < 31250)

  float* meanp = out;
  float* varp  = out + U_DIM * 64;
  const f32x4 zf4 = {0.f, 0.f, 0.f, 0.f};

  // ---- preload first tile's X rows (fp32, converted at loop head)
  float4 xr[8];
  {
    const float* xp = X + (size_t)(T * 16 + n) * 128 + q * 8;
#pragma unroll
    for (int kt = 0; kt < 4; ++kt) {
      xr[kt * 2]     = *(const float4*)(xp + kt * 32);
      xr[kt * 2 + 1] = *(const float4*)(xp + kt * 32 + 4);
    }
  }

  while (true) {
    // -- convert current tile to bf16 A-frags
    bf16x8 a_m[4], a_sq[4];
#pragma unroll
    for (int kt = 0; kt < 4; ++kt) {
      float xf[8];
      *(float4*)&xf[0] = xr[kt * 2];
      *(float4*)&xf[4] = xr[kt * 2 + 1];
#pragma unroll
      for (int u = 0; u < 8; ++u) {
        a_m[kt][u]  = f2bf(xf[u]);
        a_sq[kt][u] = f2bf(xf[u] * xf[u]);
      }
    }

    const int Tcur = T;
    const int Tn   = T + 2048;
    if (Tn < NT16) {                     // issue next tile's loads early (T14)
      const float* xp = X + (size_t)(Tn * 16 + n) * 128 + q * 8;
#pragma unroll
      for (int kt = 0; kt < 4; ++kt) {
        xr[kt * 2]     = *(const float4*)(xp + kt * 32);
        xr[kt * 2 + 1] = *(const float4*)(xp + kt * 32 + 4);
      }
    }

    f32x4 accm1[4], accv1[4];
#pragma unroll
    for (int c = 0; c < 4; ++c) { accm1[c] = zf4; accv1[c] = zf4; }

#pragma unroll
    for (int rc = 0; rc < 8; ++rc) {
      const short* st = &stage[rc * 8192];

      // -- layer 0 partial: 16 rows x 32 cols, K=128, weights from LDS
      f32x4 accm0[2], accv0[2];
      accm0[0] = zf4; accm0[1] = zf4; accv0[0] = zf4; accv0[1] = zf4;
#pragma unroll
      for (int kt = 0; kt < 4; ++kt) {
#pragma unroll
        for (int ct = 0; ct < 2; ++ct) {
          bf16x8 bm = *(const bf16x8*)&st[((0 * 2 + ct) * 4 + kt) * 512 + lane8];
          bf16x8 bv = *(const bf16x8*)&st[((1 * 2 + ct) * 4 + kt) * 512 + lane8];
          accm0[ct] = __builtin_amdgcn_mfma_f32_16x16x32_bf16(a_m[kt],  bm, accm0[ct], 0, 0, 0);
          accv0[ct] = __builtin_amdgcn_mfma_f32_16x16x32_bf16(a_sq[kt], bv, accv0[ct], 0, 0, 0);
        }
      }

      // -- gate + transpose via wave-private LDS (D: row=q*4+reg, col=ct*16+n)
#pragma unroll
      for (int ct = 0; ct < 2; ++ct) {
        const int c = ct * 16 + n;
#pragma unroll
        for (int reg = 0; reg < 4; ++reg) {
          float m = accm0[ct][reg], v = accv0[ct][reg];
          if (!(m > 0.f)) { m = 0.f; v = 0.f; }
          const int row = q * 4 + reg;
          ldsM[w][row * 40 + c] = f2bf(m);
          ldsV[w][row * 40 + c] = f2bf(v);
        }
      }
      // same-wave RAW: compiler inserts lgkmcnt wait; no barrier needed
      bf16x8 am = *(const bf16x8*)&ldsM[w][n * 40 + q * 8];
      bf16x8 av = *(const bf16x8*)&ldsV[w][n * 40 + q * 8];
      bf16x8 asq;
#pragma unroll
      for (int u = 0; u < 8; ++u) {
        float f = bf2f(am[u]);
        asq[u] = f2bf(f * f);
      }

      // -- layer 1 partial: weights from global (packed 1 KB frags, cache-hot)
      const short* l1b = wgt + 65536 + rc * 6144 + lane8;
#pragma unroll
      for (int ct1 = 0; ct1 < 4; ++ct1) {
        const short* fb = l1b + ct1 * 1536;
        bf16x8 b1 = *(const bf16x8*)&fb[0];
        bf16x8 b2 = *(const bf16x8*)&fb[512];
        bf16x8 b3 = *(const bf16x8*)&fb[1024];
        accm1[ct1] = __builtin_amdgcn_mfma_f32_16x16x32_bf16(am,  b1, accm1[ct1], 0, 0, 0);
        accv1[ct1] = __builtin_amdgcn_mfma_f32_16x16x32_bf16(av,  b2, accv1[ct1], 0, 0, 0);
        accv1[ct1] = __builtin_amdgcn_mfma_f32_16x16x32_bf16(asq, b3, accv1[ct1], 0, 0, 0);
      }
    }

    // ---- epilogue: run-aggregated segment atomics for tile Tcur
    {
      int4 idx4 = *(const int4*)&Xidx[Tcur * 16 + q * 4];
      int uid[4] = {idx4.x, idx4.y, idx4.z, idx4.w};
#pragma unroll
      for (int ct = 0; ct < 4; ++ct) {
        const int o = ct * 16 + n;
        float sm = 0.f, sv = 0.f;
        int cur = uid[0];
#pragma unroll
        for (int reg = 0; reg < 4; ++reg) {
          float v1 = fmaxf(accv1[ct][reg], EPSV);
          float inv = 1.0f / v1;
          float mi  = accm1[ct][reg] * inv;
          if (uid[reg] != cur) {
            atomicAdd(&meanp[cur * 64 + o], sm);
            atomicAdd(&varp[cur * 64 + o], sv);
            sm = 0.f; sv = 0.f; cur = uid[reg];
          }
          sm += mi; sv += inv;
        }
        atomicAdd(&meanp[cur * 64 + o], sm);
        atomicAdd(&varp[cur * 64 + o], sv);
      }
    }

    if (Tn >= NT16) break;
    T = Tn;
  }
}

// emb_var = 1/(sum_inv + eps); emb_mean = sum_m_inv * emb_var  (in place)
__global__ void finalize(float* __restrict__ out) {
  int i = blockIdx.x * blockDim.x + threadIdx.x;
  if (i < U_DIM * 64) {
    float s = out[U_DIM * 64 + i];
    float var = 1.0f / (s + EPSV);
    out[U_DIM * 64 + i] = var;
    out[i] = out[i] * var;
  }
}

extern "C" void kernel_launch(void* const* d_in, const int* in_sizes, int n_in,
                              void* d_out, int out_size, void* d_ws, size_t ws_size,
                              hipStream_t stream) {
  (void)in_sizes; (void)n_in; (void)out_size; (void)ws_size;
  const float* X    = (const float*)d_in[0];
  const int*   Xidx = (const int*)d_in[1];
  const float* Wmu0 = (const float*)d_in[2];
  const float* Wlv0 = (const float*)d_in[3];
  const float* Wmu1 = (const float*)d_in[4];
  const float* Wlv1 = (const float*)d_in[5];
  float* out = (float*)d_out;
  short* wgt = (short*)d_ws;            // 224 KB workspace (packed weights)

  hipMemsetAsync(d_out, 0, (size_t)U_DIM * 64 * 2 * sizeof(float), stream);
  prep_weights<<<192, 256, 0, stream>>>(Wmu0, Wlv0, Wmu1, Wlv1, wgt);
  // 256 blocks x 8 waves = 2048 persistent wave slots, 151.5 KB LDS ->
  // 1 block/CU; each wave strides tiles gw, gw+2048, ... (15-16 tiles)
  vb_fused<<<256, 512, 0, stream>>>(X, Xidx, wgt, out);
  finalize<<<(U_DIM * 64 + 255) / 256, 256, 0, stream>>>(out);
}

// Round 2
// 735.876 us; speedup vs baseline: 1.1832x; 1.1832x over previous
//
#include <hip/hip_runtime.h>
#include <stdint.h>

// Problem constants: N=500000, D_IN=128, R=256, D_OUT=64, U=10000
#define N_ROWS 500000
#define U_DIM 10000
#define EPSV 1e-8f
#define NT32 15625            // 32-row wave-tiles (exact: 500000/32)

typedef __attribute__((ext_vector_type(8))) short bf16x8;   // 8 bf16 = 4 VGPRs
typedef __attribute__((ext_vector_type(4))) float f32x4;    // MFMA 16x16 accumulator

__device__ __forceinline__ short f2bf(float f) {
  unsigned u = __float_as_uint(f);
  u += 0x7fffu + ((u >> 16) & 1u);
  return (short)(u >> 16);
}
__device__ __forceinline__ float bf2f(short s) {
  return __uint_as_float(((unsigned)(unsigned short)s) << 16);
}

// Packed weight layouts in d_ws (shorts), frag-major (one wave load = 1 KB):
//   L0: [rc=8][mat=2][ct=2][kt=4][lane=64][u=8]  @ 0      (128 KB; 16 KB/rc chunk)
//   L1: [rc=8][ct1=4][mat=3][lane=64][u=8]       @ 65536  (96 KB)
// lane = q*16 + n;  element: c/o = ct*16+n,  k/j = kt*32 + q*8 + u.
__global__ void prep_weights(const float* __restrict__ Wmu0,
                             const float* __restrict__ Wlv0,
                             const float* __restrict__ Wmu1,
                             const float* __restrict__ Wlv1,
                             short* __restrict__ wgt) {
  int i = blockIdx.x * blockDim.x + threadIdx.x;
  if (i < 32768) {                       // L0 element: k = i>>8 (0..127), c = i&255
    int c = i & 255, k = i >> 8;
    int rc = c >> 5, ct = (c >> 4) & 1, n = c & 15;
    int kt = k >> 5, q = (k >> 3) & 3, u = k & 7;
    int lane = q * 16 + n;
    float mu = Wmu0[k * 256 + c];
    float ev = __expf(Wlv0[k * 256 + c]);
    wgt[((((rc * 2 + 0) * 2 + ct) * 4 + kt) * 64 + lane) * 8 + u] = f2bf(mu);
    wgt[((((rc * 2 + 1) * 2 + ct) * 4 + kt) * 64 + lane) * 8 + u] = f2bf(ev);
  } else if (i < 49152) {                // L1 element: j = (i-32768)>>6, o = &63
    int i2 = i - 32768;
    int o = i2 & 63, j = i2 >> 6;
    int rc = j >> 5, q = (j >> 3) & 3, u = j & 7;
    int ct1 = o >> 4, n = o & 15;
    int lane = q * 16 + n;
    float mu = Wmu1[j * 64 + o];
    float ev = __expf(Wlv1[j * 64 + o]);
    int b = 65536 + (((rc * 4 + ct1) * 3 + 0) * 64 + lane) * 8 + u;
    wgt[b]        = f2bf(mu);            // mat 0: mu1
    wgt[b + 512]  = f2bf(mu * mu + ev);  // mat 1: mu1^2 + var
    wgt[b + 1024] = f2bf(ev);            // mat 2: var
  }
}

// Fused 2-layer VB kernel — R6: R4 structure (4 waves/block, per-rc dbuf
// staging, 3 blocks/CU) but each wave owns TWO 16-row tiles (32 rows).
// Rationale: at M=16, every staged B-frag fed exactly 1 MFMA; with 2
// row-tiles the same LDS frag reads, same L1-frag global loads, and the
// same per-rc barrier feed 2x the MFMAs (56/rc vs 28/rc). Barrier+drain
// count per row of output halves. R5's barrier-free 1-block/CU variant
// proved occupancy (12 waves/CU) matters more than barrier elimination:
// it halved MfmaUtil. LDS = 32K stage + 20K transpose = 52K -> 3 blk/CU.
__global__ __launch_bounds__(256, 3) void vb_fused(
    const float* __restrict__ X, const int* __restrict__ Xidx,
    const short* __restrict__ wgt, float* __restrict__ out) {
  __shared__ __align__(16) short stage[2][8192];      // 2 x 16 KB L0 chunk
  __shared__ __align__(16) short ldsM[4][2][16 * 40]; // per-wave,per-tile transpose
  __shared__ __align__(16) short ldsV[4][2][16 * 40];

  const int tid  = threadIdx.x;
  const int w    = tid >> 6;
  const int lane = tid & 63;
  const int n    = lane & 15;
  const int q    = lane >> 4;
  const int T    = blockIdx.x * 4 + w;             // 32-row wave-tile id
  const bool active = (T < NT32);
  const int row0 = active ? T * 32 : (N_ROWS - 32);  // tail waves: dup rows, no atomics

  const f32x4 zf4 = {0.f, 0.f, 0.f, 0.f};
  const int lane8 = lane * 8;

  // ---- X prologue: 32 rows once, pre-convert to bf16 A-frags (64 VGPRs)
  bf16x8 a_m[2][4], a_sq[2][4];
#pragma unroll
  for (int t = 0; t < 2; ++t) {
    const float* xr = X + (size_t)(row0 + t * 16 + n) * 128;
#pragma unroll
    for (int kt = 0; kt < 4; ++kt) {
      float xf[8];
      *(float4*)&xf[0] = *(const float4*)&xr[kt * 32 + q * 8];
      *(float4*)&xf[4] = *(const float4*)&xr[kt * 32 + q * 8 + 4];
#pragma unroll
      for (int u = 0; u < 8; ++u) {
        a_m[t][kt][u]  = f2bf(xf[u]);
        a_sq[t][kt][u] = f2bf(xf[u] * xf[u]);
      }
    }
  }

  f32x4 accm1[2][4], accv1[2][4];
#pragma unroll
  for (int t = 0; t < 2; ++t)
#pragma unroll
    for (int c = 0; c < 4; ++c) { accm1[t][c] = zf4; accv1[t][c] = zf4; }

  // ---- async staging: 4 segments x (256 thr x 16 B) = 16 KB per rc-chunk.
  const char* gbase = (const char*)wgt;
#define ISSUE_STAGE(rc_, buf_)                                                 \
  do {                                                                         \
    _Pragma("unroll")                                                          \
    for (int s_ = 0; s_ < 4; ++s_) {                                           \
      __builtin_amdgcn_global_load_lds(                                        \
          (const __attribute__((address_space(1))) unsigned int*)              \
              (gbase + (rc_) * 16384 + s_ * 4096 + tid * 16),                  \
          (__attribute__((address_space(3))) unsigned int*)                    \
              ((char*)&stage[buf_][0] + s_ * 4096 + (w << 10)),                \
          16, 0, 0);                                                           \
    }                                                                          \
  } while (0)

  ISSUE_STAGE(0, 0);

#pragma unroll
  for (int rc = 0; rc < 8; ++rc) {
    // barrier: compiler drains vmcnt(0) before s_barrier -> stage[rc&1] is
    // complete+visible; all waves finished reading stage[(rc+1)&1] already.
    __syncthreads();
    if (rc < 7) ISSUE_STAGE(rc + 1, (rc + 1) & 1);

    const short* st = &stage[rc & 1][0];

    // -- layer 0 partial: 32 rows x 32 cols, K=128. ct-outer so only one
    // ct's accumulators (16 VGPRs) are live at a time; each bm/bv LDS read
    // feeds 2 MFMAs (one per row-tile).
#pragma unroll
    for (int ct = 0; ct < 2; ++ct) {
      f32x4 am0_0 = zf4, am0_1 = zf4, av0_0 = zf4, av0_1 = zf4;
#pragma unroll
      for (int kt = 0; kt < 4; ++kt) {
        bf16x8 bm = *(const bf16x8*)&st[((0 * 2 + ct) * 4 + kt) * 512 + lane8];
        bf16x8 bv = *(const bf16x8*)&st[((1 * 2 + ct) * 4 + kt) * 512 + lane8];
        am0_0 = __builtin_amdgcn_mfma_f32_16x16x32_bf16(a_m[0][kt],  bm, am0_0, 0, 0, 0);
        am0_1 = __builtin_amdgcn_mfma_f32_16x16x32_bf16(a_m[1][kt],  bm, am0_1, 0, 0, 0);
        av0_0 = __builtin_amdgcn_mfma_f32_16x16x32_bf16(a_sq[0][kt], bv, av0_0, 0, 0, 0);
        av0_1 = __builtin_amdgcn_mfma_f32_16x16x32_bf16(a_sq[1][kt], bv, av0_1, 0, 0, 0);
      }
      // gate + transpose store (D: row=q*4+reg, col=ct*16+n), both tiles
      const int c = ct * 16 + n;
#pragma unroll
      for (int reg = 0; reg < 4; ++reg) {
        const int row = q * 4 + reg;
        float m0 = am0_0[reg], v0 = av0_0[reg];
        if (!(m0 > 0.f)) { m0 = 0.f; v0 = 0.f; }
        ldsM[w][0][row * 40 + c] = f2bf(m0);
        ldsV[w][0][row * 40 + c] = f2bf(v0);
        float m1 = am0_1[reg], v1 = av0_1[reg];
        if (!(m1 > 0.f)) { m1 = 0.f; v1 = 0.f; }
        ldsM[w][1][row * 40 + c] = f2bf(m1);
        ldsV[w][1][row * 40 + c] = f2bf(v1);
      }
    }

    // same-wave RAW: compiler inserts lgkmcnt wait; no barrier needed
    bf16x8 am[2], av[2], asq[2];
#pragma unroll
    for (int t = 0; t < 2; ++t) {
      am[t] = *(const bf16x8*)&ldsM[w][t][n * 40 + q * 8];
      av[t] = *(const bf16x8*)&ldsV[w][t][n * 40 + q * 8];
#pragma unroll
      for (int u = 0; u < 8; ++u) {
        float f = bf2f(am[t][u]);
        asq[t][u] = f2bf(f * f);
      }
    }

    // -- layer 1 partial: weights from global (packed 1 KB frags, L1/L2-hot);
    // each frag triple feeds both row-tiles (6 MFMAs per 3 loads).
    const short* l1b = wgt + 65536 + rc * 6144 + lane8;
#pragma unroll
    for (int ct1 = 0; ct1 < 4; ++ct1) {
      const short* fb = l1b + ct1 * 1536;
      bf16x8 b1 = *(const bf16x8*)&fb[0];
      bf16x8 b2 = *(const bf16x8*)&fb[512];
      bf16x8 b3 = *(const bf16x8*)&fb[1024];
#pragma unroll
      for (int t = 0; t < 2; ++t) {
        accm1[t][ct1] = __builtin_amdgcn_mfma_f32_16x16x32_bf16(am[t],  b1, accm1[t][ct1], 0, 0, 0);
        accv1[t][ct1] = __builtin_amdgcn_mfma_f32_16x16x32_bf16(av[t],  b2, accv1[t][ct1], 0, 0, 0);
        accv1[t][ct1] = __builtin_amdgcn_mfma_f32_16x16x32_bf16(asq[t], b3, accv1[t][ct1], 0, 0, 0);
      }
    }
  }
#undef ISSUE_STAGE

  // ---- epilogue: run-aggregated segment atomics (tail-dup waves skip)
  if (!active) return;
  float* meanp = out;
  float* varp  = out + U_DIM * 64;
#pragma unroll
  for (int t = 0; t < 2; ++t) {
    int4 idx4 = *(const int4*)&Xidx[row0 + t * 16 + q * 4];
    int uid[4] = {idx4.x, idx4.y, idx4.z, idx4.w};
#pragma unroll
    for (int ct = 0; ct < 4; ++ct) {
      const int o = ct * 16 + n;
      float sm = 0.f, sv = 0.f;
      int cur = uid[0];
#pragma unroll
      for (int reg = 0; reg < 4; ++reg) {
        float v1 = fmaxf(accv1[t][ct][reg], EPSV);
        float inv = 1.0f / v1;
        float mi  = accm1[t][ct][reg] * inv;
        if (uid[reg] != cur) {
          atomicAdd(&meanp[cur * 64 + o], sm);
          atomicAdd(&varp[cur * 64 + o], sv);
          sm = 0.f; sv = 0.f; cur = uid[reg];
        }
        sm += mi; sv += inv;
      }
      atomicAdd(&meanp[cur * 64 + o], sm);
      atomicAdd(&varp[cur * 64 + o], sv);
    }
  }
}

// emb_var = 1/(sum_inv + eps); emb_mean = sum_m_inv * emb_var  (in place)
__global__ void finalize(float* __restrict__ out) {
  int i = blockIdx.x * blockDim.x + threadIdx.x;
  if (i < U_DIM * 64) {
    float s = out[U_DIM * 64 + i];
    float var = 1.0f / (s + EPSV);
    out[U_DIM * 64 + i] = var;
    out[i] = out[i] * var;
  }
}

extern "C" void kernel_launch(void* const* d_in, const int* in_sizes, int n_in,
                              void* d_out, int out_size, void* d_ws, size_t ws_size,
                              hipStream_t stream) {
  (void)in_sizes; (void)n_in; (void)out_size; (void)ws_size;
  const float* X    = (const float*)d_in[0];
  const int*   Xidx = (const int*)d_in[1];
  const float* Wmu0 = (const float*)d_in[2];
  const float* Wlv0 = (const float*)d_in[3];
  const float* Wmu1 = (const float*)d_in[4];
  const float* Wlv1 = (const float*)d_in[5];
  float* out = (float*)d_out;
  short* wgt = (short*)d_ws;            // 224 KB workspace (packed weights)

  hipMemsetAsync(d_out, 0, (size_t)U_DIM * 64 * 2 * sizeof(float), stream);
  prep_weights<<<192, 256, 0, stream>>>(Wmu0, Wlv0, Wmu1, Wlv1, wgt);
  // 15625 32-row wave-tiles / 4 per block -> 3907 blocks (tail clamped+guarded)
  vb_fused<<<3907, 256, 0, stream>>>(X, Xidx, wgt, out);
  finalize<<<(U_DIM * 64 + 255) / 256, 256, 0, stream>>>(out);
}

// Round 4
// 553.117 us; speedup vs baseline: 1.5741x; 1.3304x over previous
//
#include <hip/hip_runtime.h>
#include <stdint.h>

// Problem constants: N=500000, D_IN=128, R=256, D_OUT=64, U=10000
#define N_ROWS 500000
#define U_DIM 10000
#define EPSV 1e-8f
#define NT16 31250            // 16-row wave-tiles (exact: 500000/16)

typedef __attribute__((ext_vector_type(8))) short bf16x8;   // 8 bf16 = 4 VGPRs
typedef __attribute__((ext_vector_type(4))) float f32x4;    // MFMA 16x16 accumulator

__device__ __forceinline__ short f2bf(float f) {
  unsigned u = __float_as_uint(f);
  u += 0x7fffu + ((u >> 16) & 1u);
  return (short)(u >> 16);
}
__device__ __forceinline__ float bf2f(short s) {
  return __uint_as_float(((unsigned)(unsigned short)s) << 16);
}

// Packed weight layouts in d_ws (shorts), frag-major (one wave load = 1 KB):
//   L0: [rc=8][mat=2][ct=2][kt=4][lane=64][u=8]  @ 0      (128 KB; 16 KB/rc chunk)
//   L1: [rc=8][ct1=4][mat=3][lane=64][u=8]       @ 65536  (96 KB)
// lane = q*16 + n;  element: c/o = ct*16+n,  k/j = kt*32 + q*8 + u.
__global__ void prep_weights(const float* __restrict__ Wmu0,
                             const float* __restrict__ Wlv0,
                             const float* __restrict__ Wmu1,
                             const float* __restrict__ Wlv1,
                             short* __restrict__ wgt) {
  int i = blockIdx.x * blockDim.x + threadIdx.x;
  if (i < 32768) {                       // L0 element: k = i>>8 (0..127), c = i&255
    int c = i & 255, k = i >> 8;
    int rc = c >> 5, ct = (c >> 4) & 1, n = c & 15;
    int kt = k >> 5, q = (k >> 3) & 3, u = k & 7;
    int lane = q * 16 + n;
    float mu = Wmu0[k * 256 + c];
    float ev = __expf(Wlv0[k * 256 + c]);
    wgt[((((rc * 2 + 0) * 2 + ct) * 4 + kt) * 64 + lane) * 8 + u] = f2bf(mu);
    wgt[((((rc * 2 + 1) * 2 + ct) * 4 + kt) * 64 + lane) * 8 + u] = f2bf(ev);
  } else if (i < 49152) {                // L1 element: j = (i-32768)>>6, o = &63
    int i2 = i - 32768;
    int o = i2 & 63, j = i2 >> 6;
    int rc = j >> 5, q = (j >> 3) & 3, u = j & 7;
    int ct1 = o >> 4, n = o & 15;
    int lane = q * 16 + n;
    float mu = Wmu1[j * 64 + o];
    float ev = __expf(Wlv1[j * 64 + o]);
    int b = 65536 + (((rc * 4 + ct1) * 3 + 0) * 64 + lane) * 8 + u;
    wgt[b]        = f2bf(mu);            // mat 0: mu1
    wgt[b + 512]  = f2bf(mu * mu + ev);  // mat 1: mu1^2 + var
    wgt[b + 1024] = f2bf(ev);            // mat 2: var
  }
}

// Fused 2-layer VB kernel — R7 resubmit (R3 bench was an infra failure:
// "container failed twice", no compile/test error; kernel sync structure
// is identical to the proven 310 us R4). Exact R4 structure (M=16/wave,
// per-rc double-buffered global_load_lds staging, one barrier/rc) but LDS
// trimmed 43008 -> 40960 B so FOUR blocks/CU fit exactly (4 x 40960 =
// 163840 = full 160 KiB). R4 was latency-bound: issue util 43% with only
// 3 waves/SIMD covering ~120-200 cyc ds_read/L2 chains. R5 (8 waves, no
// barrier, 1 blk/CU) and R6 (2 tiles/wave -> spills, hbm_bytes 5.6x)
// both proved occupancy is the binding resource. Transpose panels:
// stride 40 -> 32 with XOR swizzle (store col ^ (q<<3), read offset
// (q ^ (n>>2))*8): b128 reads stay dense per-lane; stores 4-way b16,
// same as R4's stride-40 stores.
__global__ __launch_bounds__(256, 4) void vb_fused(
    const float* __restrict__ X, const int* __restrict__ Xidx,
    const short* __restrict__ wgt, float* __restrict__ out) {
  __shared__ __align__(16) short stage[2][8192];   // 2 x 16 KB L0 chunk
  __shared__ __align__(16) short ldsM[4][512];     // per-wave 16x32 transpose
  __shared__ __align__(16) short ldsV[4][512];

  const int tid  = threadIdx.x;
  const int w    = tid >> 6;
  const int lane = tid & 63;
  const int n    = lane & 15;
  const int q    = lane >> 4;
  const int T    = blockIdx.x * 4 + w;             // wave-tile id
  const bool active = (T < NT16);
  const int row0 = active ? T * 16 : (N_ROWS - 16);  // tail waves: dup rows, no atomics

  const f32x4 zf4 = {0.f, 0.f, 0.f, 0.f};
  const int lane8 = lane * 8;

  // ---- X prologue: 16 rows once, pre-convert to bf16 A-frags (32 VGPRs)
  bf16x8 a_m[4], a_sq[4];
  {
    const float* xr = X + (size_t)(row0 + n) * 128;
#pragma unroll
    for (int kt = 0; kt < 4; ++kt) {
      float xf[8];
      *(float4*)&xf[0] = *(const float4*)&xr[kt * 32 + q * 8];
      *(float4*)&xf[4] = *(const float4*)&xr[kt * 32 + q * 8 + 4];
#pragma unroll
      for (int u = 0; u < 8; ++u) {
        a_m[kt][u]  = f2bf(xf[u]);
        a_sq[kt][u] = f2bf(xf[u] * xf[u]);
      }
    }
  }

  f32x4 accm1[4], accv1[4];
#pragma unroll
  for (int c = 0; c < 4; ++c) { accm1[c] = zf4; accv1[c] = zf4; }

  // ---- async staging: 4 segments x (256 thr x 16 B) = 16 KB per rc-chunk.
  const char* gbase = (const char*)wgt;
#define ISSUE_STAGE(rc_, buf_)                                                 \
  do {                                                                         \
    _Pragma("unroll")                                                          \
    for (int s_ = 0; s_ < 4; ++s_) {                                           \
      __builtin_amdgcn_global_load_lds(                                        \
          (const __attribute__((address_space(1))) unsigned int*)              \
              (gbase + (rc_) * 16384 + s_ * 4096 + tid * 16),                  \
          (__attribute__((address_space(3))) unsigned int*)                    \
              ((char*)&stage[buf_][0] + s_ * 4096 + (w << 10)),                \
          16, 0, 0);                                                           \
    }                                                                          \
  } while (0)

  ISSUE_STAGE(0, 0);

#pragma unroll
  for (int rc = 0; rc < 8; ++rc) {
    // barrier: compiler drains vmcnt(0) before s_barrier -> stage[rc&1] is
    // complete+visible; all waves have finished reading stage[(rc+1)&1]
    // (their reads were iteration rc-1, lgkmcnt drained before the barrier).
    __syncthreads();
    if (rc < 7) ISSUE_STAGE(rc + 1, (rc + 1) & 1);

    const short* st = &stage[rc & 1][0];

    // -- layer 0 partial: 16 rows x 32 cols, K=128, weights from LDS
    f32x4 accm0[2], accv0[2];
    accm0[0] = zf4; accm0[1] = zf4; accv0[0] = zf4; accv0[1] = zf4;
#pragma unroll
    for (int kt = 0; kt < 4; ++kt) {
#pragma unroll
      for (int ct = 0; ct < 2; ++ct) {
        bf16x8 bm = *(const bf16x8*)&st[((0 * 2 + ct) * 4 + kt) * 512 + lane8];
        bf16x8 bv = *(const bf16x8*)&st[((1 * 2 + ct) * 4 + kt) * 512 + lane8];
        accm0[ct] = __builtin_amdgcn_mfma_f32_16x16x32_bf16(a_m[kt],  bm, accm0[ct], 0, 0, 0);
        accv0[ct] = __builtin_amdgcn_mfma_f32_16x16x32_bf16(a_sq[kt], bv, accv0[ct], 0, 0, 0);
      }
    }

    // -- gate + transpose via wave-private LDS, stride 32 + XOR swizzle
    // (D: row=q*4+reg, col=ct*16+n; store at col ^ (q<<3))
#pragma unroll
    for (int ct = 0; ct < 2; ++ct) {
      const int csw = (ct * 16 + n) ^ (q << 3);
#pragma unroll
      for (int reg = 0; reg < 4; ++reg) {
        float m = accm0[ct][reg], v = accv0[ct][reg];
        if (!(m > 0.f)) { m = 0.f; v = 0.f; }
        const int row = q * 4 + reg;
        ldsM[w][row * 32 + csw] = f2bf(m);
        ldsV[w][row * 32 + csw] = f2bf(v);
      }
    }
    // same-wave RAW: compiler inserts lgkmcnt wait; no barrier needed.
    // read row n, cols q*8..q*8+7 live at n*32 + ((q ^ (n>>2))*8) .. +7
    const int roff = n * 32 + (((q ^ (n >> 2)) & 3) << 3);
    bf16x8 am = *(const bf16x8*)&ldsM[w][roff];
    bf16x8 av = *(const bf16x8*)&ldsV[w][roff];
    bf16x8 asq;
#pragma unroll
    for (int u = 0; u < 8; ++u) {
      float f = bf2f(am[u]);
      asq[u] = f2bf(f * f);
    }

    // -- layer 1 partial: weights from global (packed 1 KB frags, L1-resident)
    const short* l1b = wgt + 65536 + rc * 6144 + lane8;
#pragma unroll
    for (int ct1 = 0; ct1 < 4; ++ct1) {
      const short* fb = l1b + ct1 * 1536;
      bf16x8 b1 = *(const bf16x8*)&fb[0];
      bf16x8 b2 = *(const bf16x8*)&fb[512];
      bf16x8 b3 = *(const bf16x8*)&fb[1024];
      accm1[ct1] = __builtin_amdgcn_mfma_f32_16x16x32_bf16(am,  b1, accm1[ct1], 0, 0, 0);
      accv1[ct1] = __builtin_amdgcn_mfma_f32_16x16x32_bf16(av,  b2, accv1[ct1], 0, 0, 0);
      accv1[ct1] = __builtin_amdgcn_mfma_f32_16x16x32_bf16(asq, b3, accv1[ct1], 0, 0, 0);
    }
  }
#undef ISSUE_STAGE

  // ---- epilogue: run-aggregated segment atomics (tail-dup waves skip)
  if (!active) return;
  float* meanp = out;
  float* varp  = out + U_DIM * 64;
  int4 idx4 = *(const int4*)&Xidx[row0 + q * 4];
  int uid[4] = {idx4.x, idx4.y, idx4.z, idx4.w};
#pragma unroll
  for (int ct = 0; ct < 4; ++ct) {
    const int o = ct * 16 + n;
    float sm = 0.f, sv = 0.f;
    int cur = uid[0];
#pragma unroll
    for (int reg = 0; reg < 4; ++reg) {
      float v1 = fmaxf(accv1[ct][reg], EPSV);
      float inv = 1.0f / v1;
      float mi  = accm1[ct][reg] * inv;
      if (uid[reg] != cur) {
        atomicAdd(&meanp[cur * 64 + o], sm);
        atomicAdd(&varp[cur * 64 + o], sv);
        sm = 0.f; sv = 0.f; cur = uid[reg];
      }
      sm += mi; sv += inv;
    }
    atomicAdd(&meanp[cur * 64 + o], sm);
    atomicAdd(&varp[cur * 64 + o], sv);
  }
}

// emb_var = 1/(sum_inv + eps); emb_mean = sum_m_inv * emb_var  (in place)
__global__ void finalize(float* __restrict__ out) {
  int i = blockIdx.x * blockDim.x + threadIdx.x;
  if (i < U_DIM * 64) {
    float s = out[U_DIM * 64 + i];
    float var = 1.0f / (s + EPSV);
    out[U_DIM * 64 + i] = var;
    out[i] = out[i] * var;
  }
}

extern "C" void kernel_launch(void* const* d_in, const int* in_sizes, int n_in,
                              void* d_out, int out_size, void* d_ws, size_t ws_size,
                              hipStream_t stream) {
  (void)in_sizes; (void)n_in; (void)out_size; (void)ws_size;
  const float* X    = (const float*)d_in[0];
  const int*   Xidx = (const int*)d_in[1];
  const float* Wmu0 = (const float*)d_in[2];
  const float* Wlv0 = (const float*)d_in[3];
  const float* Wmu1 = (const float*)d_in[4];
  const float* Wlv1 = (const float*)d_in[5];
  float* out = (float*)d_out;
  short* wgt = (short*)d_ws;            // 224 KB workspace (packed weights)

  hipMemsetAsync(d_out, 0, (size_t)U_DIM * 64 * 2 * sizeof(float), stream);
  prep_weights<<<192, 256, 0, stream>>>(Wmu0, Wlv0, Wmu1, Wlv1, wgt);
  // 31250 16-row wave-tiles / 4 per block -> 7813 blocks (tail clamped+guarded)
  vb_fused<<<7813, 256, 0, stream>>>(X, Xidx, wgt, out);
  finalize<<<(U_DIM * 64 + 255) / 256, 256, 0, stream>>>(out);
}